// Round 7
// baseline (361.331 us; speedup 1.0000x reference)
//
#include <hip/hip_runtime.h>
#include <hip/hip_bf16.h>

// GAT layer, B=2 N=4096 F_IN=256 F_OUT=64 H=4.
// prep: x = h@W, xT bf16 [b][f][n], elT/erT f32 pre-scaled by log2e.
// main: BARRIER-FREE, LDS-FREE. wave = head, 16 i-rows/block, j-halved grid
//       1024 (all co-resident). adj (the only HBM stream, zero-reuse) and er
//       are register-prefetched distance-1; xt A-frags direct from L2.
//       Scores in regs -> P-frag; swapped PV (A=xt,B=P); denom via ones-MFMA.
// fin:  combine 2 j-partials, /denom, +bias, elu.

#define NN 4096
#define NH 4
#define NJQ 2
#define NT 32                    // tiles of 64 j over 2048-wide half
#define LOG2E 1.4426950408889634f

typedef __bf16 bf16x8 __attribute__((ext_vector_type(8)));
typedef unsigned short ushortx8 __attribute__((ext_vector_type(8)));
typedef unsigned short us4 __attribute__((ext_vector_type(4)));
typedef float f32x4 __attribute__((ext_vector_type(4)));

__device__ __forceinline__ unsigned short f2bf(float x) {
  __hip_bfloat16 hb = __float2bfloat16(x);
  return __builtin_bit_cast(unsigned short, hb);
}

#if __has_builtin(__builtin_amdgcn_exp2f)
#define EXP2F(x) __builtin_amdgcn_exp2f(x)
#else
#define EXP2F(x) exp2f(x)
#endif

// ---------------- kernel 1: prep (unchanged, verified) ----------------
__global__ __launch_bounds__(256, 2) void gat_prep(
    const float* __restrict__ hmat, const float* __restrict__ W,
    const float* __restrict__ Wl, const float* __restrict__ Wr,
    unsigned short* __restrict__ xT, float* __restrict__ elT,
    float* __restrict__ erT)
{
  __shared__ __align__(16) float h_s[16][256];
  __shared__ float x_s[16][65];
  __shared__ float wlr_s[512];

  const int t  = threadIdx.x;
  const int wv = t >> 6;
  const int l  = t & 63;
  const int b  = blockIdx.x >> 8;
  const int i0 = (blockIdx.x & 255) << 4;

  {
    const float4* hsrc = (const float4*)(hmat + ((size_t)(b * NN + i0)) * 256);
    float4* hdst = (float4*)&h_s[0][0];
#pragma unroll
    for (int u = 0; u < 4; ++u) hdst[t + 256 * u] = hsrc[t + 256 * u];
    wlr_s[t]       = Wl[t];
    wlr_s[256 + t] = Wr[t];
  }
  __syncthreads();

  const int row0 = wv << 2;
  float acc[4] = {0.f, 0.f, 0.f, 0.f};
#pragma unroll 4
  for (int k4 = 0; k4 < 64; ++k4) {
    const float w0 = W[(k4 * 4 + 0) * 64 + l];
    const float w1 = W[(k4 * 4 + 1) * 64 + l];
    const float w2 = W[(k4 * 4 + 2) * 64 + l];
    const float w3 = W[(k4 * 4 + 3) * 64 + l];
#pragma unroll
    for (int rr = 0; rr < 4; ++rr) {
      const float4 hv = *(const float4*)&h_s[row0 + rr][k4 * 4];
      acc[rr] = fmaf(hv.x, w0, acc[rr]);
      acc[rr] = fmaf(hv.y, w1, acc[rr]);
      acc[rr] = fmaf(hv.z, w2, acc[rr]);
      acc[rr] = fmaf(hv.w, w3, acc[rr]);
    }
  }
#pragma unroll
  for (int rr = 0; rr < 4; ++rr) x_s[row0 + rr][l] = acc[rr];
  __syncthreads();

  if (t < 64) {
    const int row = t >> 2, hh = t & 3;
    float el = 0.f, er = 0.f;
#pragma unroll 8
    for (int f = 0; f < 64; ++f) {
      const float xv = x_s[row][f];
      el = fmaf(xv, wlr_s[hh * 64 + f], el);
      er = fmaf(xv, wlr_s[256 + hh * 64 + f], er);
    }
    elT[((size_t)b * NH + hh) * NN + i0 + row] = el * LOG2E;
    erT[((size_t)b * NH + hh) * NN + i0 + row] = er * LOG2E;
  }

  {
    const int f = t >> 2, q = t & 3;
    us4 pk;
#pragma unroll
    for (int rj = 0; rj < 4; ++rj) pk[rj] = f2bf(x_s[q * 4 + rj][f]);
    *(us4*)&xT[((size_t)(b * 64 + f)) * NN + i0 + q * 4] = pk;
  }
}

// ---------------- kernel 2: fused softmax + PV (barrier-free) ----------------
// grid 1024 = jh(2) x b(2) x itile(256); block 256, wave = head, 16 rows.
template <bool ATOMIC>
__global__ __launch_bounds__(256, 3) void gat_main(
    const int* __restrict__ adj, const unsigned short* __restrict__ xT,
    const float* __restrict__ elT, const float* __restrict__ erT,
    float* __restrict__ numP, float* __restrict__ denP)
{
  const int t = threadIdx.x;
  const int w = t >> 6;           // head
  const int l = t & 63;
  const int blk   = blockIdx.x;
  const int jh    = blk >> 9;
  const int b     = (blk >> 8) & 1;
  const int itile = blk & 255;
  const int i0 = itile << 4;
  const int j0 = jh << 11;        // 2048-wide j half
  const int lrow = l & 15;
  const int lk   = l >> 4;

  const float el_reg = elT[((size_t)b * NH + w) * NN + i0 + lrow];

  // per-lane base pointers (lane owns row i0+lrow, j-window lk*8 within tile)
  const int*            adjp = adj + ((size_t)(b * NN + i0 + lrow)) * NN + j0 + (lk << 3);
  const unsigned short* xtp  = xT + (size_t)b * 64 * NN + j0 + (lk << 3);
  const float*          erp  = erT + ((size_t)b * NH + w) * NN + j0 + (lk << 3);

  f32x4 acc[4] = {};
  f32x4 accd = {};
  ushortx8 ones_u;
#pragma unroll
  for (int i = 0; i < 8; ++i) ones_u[i] = 0x3F80;   // bf16 1.0
  const bf16x8 onesf = __builtin_bit_cast(bf16x8, ones_u);

  // prologue: tile-0 adj + er in regs
  int4   a0 = *(const int4*)(adjp + 0);
  int4   a1 = *(const int4*)(adjp + 4);
  int4   a2 = *(const int4*)(adjp + 32);
  int4   a3 = *(const int4*)(adjp + 36);
  float4 e0 = *(const float4*)(erp + 0);
  float4 e1 = *(const float4*)(erp + 4);
  float4 e2 = *(const float4*)(erp + 32);
  float4 e3 = *(const float4*)(erp + 36);

#pragma unroll 1
  for (int tt = 0; tt < NT; ++tt) {
    const int jt = tt << 6;

    // this tile's xt A-frags (L2-hot; land during the score VALU below)
    bf16x8 Axt[2][4];
#pragma unroll
    for (int kc = 0; kc < 2; ++kc)
#pragma unroll
      for (int fq = 0; fq < 4; ++fq)
        Axt[kc][fq] = __builtin_bit_cast(bf16x8,
            *(const ushortx8*)(xtp + (size_t)((fq << 4) + lrow) * NN + jt + (kc << 5)));

    // distance-1 prefetch: next tile's adj (HBM stream) + er
    int4 n0 = a0, n1 = a1, n2 = a2, n3 = a3;
    float4 f0 = e0, f1 = e1, f2 = e2, f3 = e3;
    if (tt + 1 < NT) {
      const int*   nb = adjp + jt + 64;
      const float* fb = erp + jt + 64;
      n0 = *(const int4*)(nb + 0);
      n1 = *(const int4*)(nb + 4);
      n2 = *(const int4*)(nb + 32);
      n3 = *(const int4*)(nb + 36);
      f0 = *(const float4*)(fb + 0);
      f1 = *(const float4*)(fb + 4);
      f2 = *(const float4*)(fb + 32);
      f3 = *(const float4*)(fb + 36);
    }

    // scores (register-only inputs) -> P-frags -> MFMA
#pragma unroll
    for (int kc = 0; kc < 2; ++kc) {
      const int4   ja = kc ? a2 : a0;
      const int4   jb = kc ? a3 : a1;
      const float4 ea = kc ? e2 : e0;
      const float4 eb = kc ? e3 : e1;

      ushortx8 pa;
#define SCORE(A_, E_, IDX) { \
      float s_  = el_reg + (E_); \
      float lr_ = fmaxf(s_, 0.2f * s_); \
      float w_  = (A_) ? EXP2F(lr_) : 0.0f; \
      pa[IDX] = f2bf(w_); }
      SCORE(ja.x, ea.x, 0) SCORE(ja.y, ea.y, 1)
      SCORE(ja.z, ea.z, 2) SCORE(ja.w, ea.w, 3)
      SCORE(jb.x, eb.x, 4) SCORE(jb.y, eb.y, 5)
      SCORE(jb.z, eb.z, 6) SCORE(jb.w, eb.w, 7)
#undef SCORE

      const bf16x8 P = __builtin_bit_cast(bf16x8, pa);
      // swapped PV: D[f][i] = sum_j xt[f][j] * P[j][i]
      accd = __builtin_amdgcn_mfma_f32_16x16x32_bf16(onesf, P, accd, 0, 0, 0);
#pragma unroll
      for (int fq = 0; fq < 4; ++fq)
        acc[fq] = __builtin_amdgcn_mfma_f32_16x16x32_bf16(
            Axt[kc][fq], P, acc[fq], 0, 0, 0);
    }

    a0 = n0; a1 = n1; a2 = n2; a3 = n3;
    e0 = f0; e1 = f1; e2 = f2; e3 = f3;
  }

  // epilogue: C row = f = fq*16 + lk*4 + rr, col = i = lrow
  if (ATOMIC) {
    const size_t obase = ((size_t)(b * NN + i0 + lrow) * NH + w) << 6;
#pragma unroll
    for (int fq = 0; fq < 4; ++fq)
#pragma unroll
      for (int rr = 0; rr < 4; ++rr)
        atomicAdd(&numP[obase + (fq << 4) + (lk << 2) + rr], acc[fq][rr]);
    if (l < 16)
      atomicAdd(&denP[((size_t)(b * NN + i0 + l)) * NH + w], accd[0]);
  } else {
    float* nb = numP + (size_t)jh * (2u * NN * NH * 64);
    const size_t obase = ((size_t)(b * NN + i0 + lrow) * NH + w) << 6;
#pragma unroll
    for (int fq = 0; fq < 4; ++fq)
      *(float4*)&nb[obase + (fq << 4) + (lk << 2)] = (float4){
          acc[fq][0], acc[fq][1], acc[fq][2], acc[fq][3]};
    if (l < 16) {
      float* db = denP + (size_t)jh * (2u * NN * NH);
      db[((size_t)(b * NN + i0 + l)) * NH + w] = accd[0];
    }
  }
}

// ---------------- kernel 3: finalize ----------------
template <bool ATOMIC>
__global__ __launch_bounds__(256) void gat_fin(
    const float* __restrict__ numP, const float* __restrict__ denP,
    const float* __restrict__ bias, float* __restrict__ out)
{
  const int g  = blockIdx.x * 256 + threadIdx.x;     // 524288 threads
  const int f4 = (g & 15) << 2;
  float4 n;
  float d;
  if (ATOMIC) {
    n = *(const float4*)&out[(size_t)g * 4];
    d = denP[g >> 4];
  } else {
    n = (float4){0.f, 0.f, 0.f, 0.f};
    d = 0.f;
#pragma unroll
    for (int q = 0; q < NJQ; ++q) {
      const float4 nq = *(const float4*)&numP[(size_t)q * (2u * NN * NH * 64) + (size_t)g * 4];
      n.x += nq.x; n.y += nq.y; n.z += nq.z; n.w += nq.w;
      d += denP[(size_t)q * (2u * NN * NH) + (g >> 4)];
    }
  }
  const float inv = 1.0f / d;
  const float4 bv = *(const float4*)&bias[f4];
  float4 v = {n.x * inv + bv.x, n.y * inv + bv.y,
              n.z * inv + bv.z, n.w * inv + bv.w};
  v.x = v.x > 0.f ? v.x : (__expf(v.x) - 1.f);
  v.y = v.y > 0.f ? v.y : (__expf(v.y) - 1.f);
  v.z = v.z > 0.f ? v.z : (__expf(v.z) - 1.f);
  v.w = v.w > 0.f ? v.w : (__expf(v.w) - 1.f);
  *(float4*)&out[(size_t)g * 4] = v;
}

extern "C" void kernel_launch(void* const* d_in, const int* in_sizes, int n_in,
                              void* d_out, int out_size, void* d_ws, size_t ws_size,
                              hipStream_t stream) {
  const int*   adj  = (const int*)d_in[0];
  const float* hmat = (const float*)d_in[1];
  const float* W    = (const float*)d_in[2];
  const float* Wl   = (const float*)d_in[3];
  const float* Wr   = (const float*)d_in[4];
  const float* bias = (const float*)d_in[5];
  float* out = (float*)d_out;

  char* wsb = (char*)d_ws;
  unsigned short* xT  = (unsigned short*)wsb;           // 1 MB
  float*          elT = (float*)(wsb + 1048576);        // 128 KB
  float*          erT = (float*)(wsb + 1179648);        // 128 KB
  float*          den = (float*)(wsb + 1310720);        // 2 x 128 KB
  float*          num = (float*)(wsb + 1572864);        // 2 x 8 MB
  const bool partial = ws_size >= 18350080ull;

  gat_prep<<<512, 256, 0, stream>>>(hmat, W, Wl, Wr, xT, elT, erT);

  if (partial) {
    gat_main<false><<<1024, 256, 0, stream>>>(adj, xT, elT, erT, num, den);
    gat_fin<false><<<2048, 256, 0, stream>>>(num, den, bias, out);
  } else {
    hipMemsetAsync(out, 0, (size_t)out_size * 4, stream);
    hipMemsetAsync(den, 0, 131072, stream);
    gat_main<true><<<1024, 256, 0, stream>>>(adj, xT, elT, erT, out, den);
    gat_fin<true><<<2048, 256, 0, stream>>>(num, den, bias, out);
  }
}